// Round 8
// baseline (12.213 us; speedup 1.0000x reference)
//
#include <hip/hip_runtime.h>
#include <math.h>

#define NPTS 1024
#define CH 256
#define CW 256
#define NSEG 8     // waves per block = point segments (128 pts each, 2 rounds)
#define CAP  68    // per-round survivor slots (<=64 survivors + pad to x4)

// Single fused kernel. 1024 blocks x 512 threads; block owns 64 consecutive
// pixels of one row (y uniform). Each of the 8 waves handles 128 points in
// 2 rounds of 64; per round: fold per-point constants in registers, run the
// exact-conservative interval cull (t0,t1 linear in x at fixed y; interval
// min |t| = 0 on sign change else min endpoint magnitude; skip iff
// min|t0|+min|t1| >= 1), ballot-compact survivor RECORDS into this wave's
// LDS list, then evaluate the list immediately (wave-uniform ds_read_b128
// broadcast). Worst case 64 survivors/round fits CAP -> no overflow branch,
// fully straight-line. Inputs for BOTH rounds are prefetched at wave start
// so round-1 load latency hides under round-0 compute. Pad records are
// all-zero => contribution exactly 0 => output identical to reference order
// up to fp-add reassociation (well within threshold).
__global__ __launch_bounds__(512) void fused_kernel(
    const float* __restrict__ loc,   // (N,2) [y,x]
    const float* __restrict__ mo,    // (N,2,2)
    const float* __restrict__ mso,   // (N,)
    const float* __restrict__ col,   // (N,3)
    const float* __restrict__ alp,   // (N,)
    float* __restrict__ out)
{
    __shared__ float4 recA[NSEG][CAP];     // t00, t10, b0, t01
    __shared__ float4 recB[NSEG][CAP];     // t11, b1, ca0, ca1
    __shared__ float  recC[NSEG][CAP];     // ca2
    __shared__ float  part[NSEG][64][3];

    int lane = threadIdx.x & 63;
    int seg  = threadIdx.x >> 6;
    int h    = blockIdx.x >> 2;
    int w0   = (blockIdx.x & 3) << 6;

    float y  = fmaf((float)h,           2.0f/255.0f, -1.0f);
    float x  = fmaf((float)(w0 + lane), 2.0f/255.0f, -1.0f);
    float x0 = fmaf((float)w0,          2.0f/255.0f, -1.0f);
    float x1 = fmaf((float)(w0 + 63),   2.0f/255.0f, -1.0f);

    unsigned long long lt = (1ull << lane) - 1ull;
    float ac0 = 0.f, ac1 = 0.f, ac2 = 0.f;

    // ---- prefetch both rounds' inputs (all coalesced, no branches) ----
    int segbase = seg << 7;
    int n0 = segbase + lane;
    int n1 = segbase + 64 + lane;
    float2 l_0  = ((const float2*)loc)[n0], l_1  = ((const float2*)loc)[n1];
    float4 m4_0 = ((const float4*)mo)[n0],  m4_1 = ((const float4*)mo)[n1];
    float  so_0 = mso[n0],                  so_1 = mso[n1];
    float  al_0 = alp[n0],                  al_1 = alp[n1];
    float  cA_0 = col[3*n0+0], cB_0 = col[3*n0+1], cC_0 = col[3*n0+2];
    float  cA_1 = col[3*n1+0], cB_1 = col[3*n1+1], cC_1 = col[3*n1+2];

    #pragma unroll
    for (int r = 0; r < 2; ++r) {
        float2 l  = r ? l_1  : l_0;
        float4 m4 = r ? m4_1 : m4_0;
        float  so = r ? so_1 : so_0;
        float  al = r ? al_1 : al_0;
        float  ca0 = (r ? cA_1 : cA_0) * al;
        float  ca1 = (r ? cB_1 : cB_0) * al;
        float  ca2 = (r ? cC_1 : cC_0) * al;

        // ---- fused prep (registers only) ----
        float  s  = 16.0f * __expf(so);           // sqrt(1024)/2 * exp(off)
        float t00 = 0.5f * (m4.x + s);
        float t01 = 0.5f *  m4.y;
        float t10 = 0.5f *  m4.z;
        float t11 = 0.5f * (m4.w + s);
        float b0  = -(l.x * t00 + l.y * t10);
        float b1  = -(l.x * t01 + l.y * t11);

        // ---- conservative cull over [x0,x1] at fixed y ----
        float c0  = fmaf(y, t00, b0);
        float c1  = fmaf(y, t01, b1);
        float g00 = fmaf(x0, t10, c0), g01 = fmaf(x1, t10, c0);
        float g10 = fmaf(x0, t11, c1), g11 = fmaf(x1, t11, c1);
        float m0 = (g00 * g01 <= 0.0f) ? 0.0f : fminf(fabsf(g00), fabsf(g01));
        float m1 = (g10 * g11 <= 0.0f) ? 0.0f : fminf(fabsf(g10), fabsf(g11));
        bool keep = (m0 + m1) < 1.0f;

        // ---- ballot compaction into this wave's list ----
        unsigned long long mk = __ballot(keep);
        int cnt = __popcll(mk);
        if (keep) {
            int slot = __popcll(mk & lt);
            recA[seg][slot] = make_float4(t00, t10, b0, t01);
            recB[seg][slot] = make_float4(t11, b1, ca0, ca1);
            recC[seg][slot] = ca2;
        }
        int cntp = (cnt + 3) & ~3;
        if (lane < cntp - cnt) {                  // zero sentinel pad
            recA[seg][cnt + lane] = make_float4(0.f, 0.f, 0.f, 0.f);
            recB[seg][cnt + lane] = make_float4(0.f, 0.f, 0.f, 0.f);
            recC[seg][cnt + lane] = 0.f;
        }

        // ---- evaluate survivors (wave-uniform LDS broadcast, 4-way ILP) ----
        for (int i = 0; i < cntp; i += 4) {
            #pragma unroll
            for (int j = 0; j < 4; ++j) {
                float4 a = recA[seg][i + j];
                float4 b = recB[seg][i + j];
                float  c = recC[seg][i + j];
                float t0 = fmaf(x, a.y, fmaf(y, a.x, a.z));
                float t1 = fmaf(x, b.x, fmaf(y, a.w, b.y));
                float m  = fmaxf(1.0f - (fabsf(t0) + fabsf(t1)), 0.0f);
                ac0 = fmaf(b.z, m, ac0);
                ac1 = fmaf(b.w, m, ac1);
                ac2 = fmaf(c,   m, ac2);
            }
        }
    }

    // ---- cross-segment reduce + sigmoid + store ----
    part[seg][lane][0] = ac0;
    part[seg][lane][1] = ac1;
    part[seg][lane][2] = ac2;
    __syncthreads();
    int t = threadIdx.x;
    if (t < 192) {
        const float* pp = &part[0][0][0];         // [seg] stride = 192 floats
        float sum = 0.f;
        #pragma unroll
        for (int k = 0; k < NSEG; ++k) sum += pp[k * 192 + t];
        out[blockIdx.x * 192 + t] = 1.0f / (1.0f + __expf(-4.0f * sum));
    }
}

extern "C" void kernel_launch(void* const* d_in, const int* in_sizes, int n_in,
                              void* d_out, int out_size, void* d_ws, size_t ws_size,
                              hipStream_t stream) {
    const float* loc = (const float*)d_in[0];
    const float* mo  = (const float*)d_in[1];
    const float* mso = (const float*)d_in[2];
    const float* col = (const float*)d_in[3];
    const float* alp = (const float*)d_in[4];
    float* out = (float*)d_out;
    (void)d_ws; (void)ws_size;

    fused_kernel<<<(CH * CW) / 64, 512, 0, stream>>>(loc, mo, mso, col, alp, out);
}

// Round 9
// 10.125 us; speedup vs baseline: 1.2062x; 1.2062x over previous
//
#include <hip/hip_runtime.h>
#include <math.h>

#define NPTS 1024
#define CH 256
#define CW 256
#define NSEG 8     // waves per block = point segments (128 pts each)
#define CAP  68    // survivor-record slots per wave (drain threshold 64 + pad)

// Single fused kernel. 1024 blocks x 512 threads; block owns 64 consecutive
// pixels of one row (y uniform). Each of the 8 waves handles 128 points in
// 2 rounds of 64:
//   - fold per-point constants in registers (incl. color*alpha, hoisted out
//     of the divergent path so all global loads issue unconditionally),
//   - exact-conservative interval cull (t0,t1 linear in x at fixed y;
//     interval min |t| = 0 on sign change else min endpoint magnitude;
//     skip iff min|t0|+min|t1| >= 1  => m <= 0 over the whole tile),
//   - ballot-compact survivor RECORDS into this wave's LDS list.
// Both rounds accumulate into ONE list; a single eval pass runs at the end
// (wave-uniform ds_read_b128 broadcast, 4-way ILP). A wave-uniform drain
// branch (taken only if >64 survivors accumulate — practically never at ~5%
// keep rate) keeps the worst case correct. Zero-pad records contribute
// exactly 0, so output matches the reference up to fp-add reassociation.
__global__ __launch_bounds__(512) void fused_kernel(
    const float* __restrict__ loc,   // (N,2) [y,x]
    const float* __restrict__ mo,    // (N,2,2)
    const float* __restrict__ mso,   // (N,)
    const float* __restrict__ col,   // (N,3)
    const float* __restrict__ alp,   // (N,)
    float* __restrict__ out)
{
    __shared__ float4 recA[NSEG][CAP];     // t00, t10, b0, t01
    __shared__ float4 recB[NSEG][CAP];     // t11, b1, ca0, ca1
    __shared__ float  recC[NSEG][CAP];     // ca2
    __shared__ float  part[NSEG][64][3];

    int lane = threadIdx.x & 63;
    int seg  = threadIdx.x >> 6;
    int h    = blockIdx.x >> 2;
    int w0   = (blockIdx.x & 3) << 6;

    float y  = fmaf((float)h,           2.0f/255.0f, -1.0f);
    float x  = fmaf((float)(w0 + lane), 2.0f/255.0f, -1.0f);
    float x0 = fmaf((float)w0,          2.0f/255.0f, -1.0f);
    float x1 = fmaf((float)(w0 + 63),   2.0f/255.0f, -1.0f);

    unsigned long long lt = (1ull << lane) - 1ull;
    int base = 0;
    float ac0 = 0.f, ac1 = 0.f, ac2 = 0.f;

    auto evalList = [&](int cntp) {
        for (int i = 0; i < cntp; i += 4) {
            #pragma unroll
            for (int j = 0; j < 4; ++j) {
                float4 a = recA[seg][i + j];   // uniform addr -> broadcast
                float4 b = recB[seg][i + j];
                float  c = recC[seg][i + j];
                float t0 = fmaf(x, a.y, fmaf(y, a.x, a.z));
                float t1 = fmaf(x, b.x, fmaf(y, a.w, b.y));
                float m  = fmaxf(1.0f - (fabsf(t0) + fabsf(t1)), 0.0f);
                ac0 = fmaf(b.z, m, ac0);
                ac1 = fmaf(b.w, m, ac1);
                ac2 = fmaf(c,   m, ac2);
            }
        }
    };

    int segbase = seg << 7;
    #pragma unroll
    for (int r = 0; r < 2; ++r) {
        int n = segbase + (r << 6) + lane;
        // ---- all loads unconditional (compiler batches them up top) ----
        float2 l  = ((const float2*)loc)[n];
        float4 m4 = ((const float4*)mo)[n];       // T00,T01,T10,T11
        float  so = mso[n];
        float  al = alp[n];
        float  ca0 = col[3*n+0] * al;
        float  ca1 = col[3*n+1] * al;
        float  ca2 = col[3*n+2] * al;

        // ---- fused prep (registers only) ----
        float  s  = 16.0f * __expf(so);           // sqrt(1024)/2 * exp(off)
        float t00 = 0.5f * (m4.x + s);
        float t01 = 0.5f *  m4.y;
        float t10 = 0.5f *  m4.z;
        float t11 = 0.5f * (m4.w + s);
        float b0  = -(l.x * t00 + l.y * t10);
        float b1  = -(l.x * t01 + l.y * t11);

        // ---- conservative cull over [x0,x1] at fixed y ----
        float c0  = fmaf(y, t00, b0);
        float c1  = fmaf(y, t01, b1);
        float g00 = fmaf(x0, t10, c0), g01 = fmaf(x1, t10, c0);
        float g10 = fmaf(x0, t11, c1), g11 = fmaf(x1, t11, c1);
        float m0 = (g00 * g01 <= 0.0f) ? 0.0f : fminf(fabsf(g00), fabsf(g01));
        float m1 = (g10 * g11 <= 0.0f) ? 0.0f : fminf(fabsf(g10), fabsf(g11));
        bool keep = (m0 + m1) < 1.0f;
        unsigned long long mk = __ballot(keep);
        int cr = __popcll(mk);

        if (base + cr > 64) {                     // wave-uniform drain (rare)
            int cntp = (base + 3) & ~3;
            if (lane < cntp - base) {
                recA[seg][base + lane] = make_float4(0.f, 0.f, 0.f, 0.f);
                recB[seg][base + lane] = make_float4(0.f, 0.f, 0.f, 0.f);
                recC[seg][base + lane] = 0.f;
            }
            evalList(cntp);
            base = 0;
        }
        if (keep) {
            int slot = base + __popcll(mk & lt);
            recA[seg][slot] = make_float4(t00, t10, b0, t01);
            recB[seg][slot] = make_float4(t11, b1, ca0, ca1);
            recC[seg][slot] = ca2;
        }
        base += cr;
    }
    {   // single eval pass for the accumulated list
        int cntp = (base + 3) & ~3;
        if (lane < cntp - base) {                 // zero sentinel pad
            recA[seg][base + lane] = make_float4(0.f, 0.f, 0.f, 0.f);
            recB[seg][base + lane] = make_float4(0.f, 0.f, 0.f, 0.f);
            recC[seg][base + lane] = 0.f;
        }
        evalList(cntp);
    }

    // ---- cross-segment reduce + sigmoid + store ----
    part[seg][lane][0] = ac0;
    part[seg][lane][1] = ac1;
    part[seg][lane][2] = ac2;
    __syncthreads();
    int t = threadIdx.x;
    if (t < 192) {
        const float* pp = &part[0][0][0];         // [seg] stride = 192 floats
        float sum = 0.f;
        #pragma unroll
        for (int k = 0; k < NSEG; ++k) sum += pp[k * 192 + t];
        out[blockIdx.x * 192 + t] = 1.0f / (1.0f + __expf(-4.0f * sum));
    }
}

extern "C" void kernel_launch(void* const* d_in, const int* in_sizes, int n_in,
                              void* d_out, int out_size, void* d_ws, size_t ws_size,
                              hipStream_t stream) {
    const float* loc = (const float*)d_in[0];
    const float* mo  = (const float*)d_in[1];
    const float* mso = (const float*)d_in[2];
    const float* col = (const float*)d_in[3];
    const float* alp = (const float*)d_in[4];
    float* out = (float*)d_out;
    (void)d_ws; (void)ws_size;

    fused_kernel<<<(CH * CW) / 64, 512, 0, stream>>>(loc, mo, mso, col, alp, out);
}